// Round 2
// baseline (526.037 us; speedup 1.0000x reference)
//
#include <hip/hip_runtime.h>

// ---------------------------------------------------------------------------
// SelfAttention: B=8, C=256, CQ=128, N=4096
//   q = Wq x + bq ; k = Wk x + bk ; v = Wv x + bv   (per-pixel 1x1 conv)
//   S[b,m,n] = q_m.k_n ; A = softmax over m (per column n)
//   O[b,c,m] = sum_n v[c,n] A[m,n] ; y = gamma*O + x
//
// Inputs may be f32 or bf16 (runtime-detected). ws = 32 MiB:
//   K0 qkv : project. q2T[b][m][c]=q*log2e, kT[b][n][c], v[b][c][n] (bf16)
//   K1 stats: r[b][n] = 1 / sum_m exp2(S2[m,n])
//   K2 scale: v *= r[n] in place
//   K3 out : S-recompute -> exp2 -> LDS C->A flip -> PV MFMA -> y = g*O + x
//
// R8 post-mortem: removing 16/24 ds_reads + ALL bank conflicts (1.7e7->0)
// changed dur 265->271us. NOT LDS-bound. Counters: MfmaUtil 21, VALU 20,
// HBM 3.9 -- nothing busy. Traffic arithmetic: out streams k(1MB)+v(1MB)
// per 64mx128c block x1024 = 2.0GB of L2/L3 traffic in 271us = 7.4TB/s;
// stats independently ~6TB/s. Cache-fabric BW bound (per-XCD WS > 4MB L2).
// R9: cut traffic via bigger tiles.
//   out: 128m x 256c blocks, 512 thr (8 waves = 2 m-halves x 4 n-strips for
//        S; 32-c strips for PV), grid 256. k+v = 3MB/block x 256 = 768MB
//        (2.6x less); ch-duplicated S-recompute gone (137->103 GF MFMA).
//        All 32 blocks/XCD share the same k/v/q 4MB -> L2-friendly.
//   stats: 128-n blocks, 8 waves x own 16-n strip, sweep all m; q loads
//        identical across waves (L1 dedup). 512MB -> 256MB. No in-loop
//        barrier, no cross-wave reduce.
// ---------------------------------------------------------------------------

typedef unsigned short u16;
typedef __attribute__((ext_vector_type(8))) short bf16x8;
typedef __attribute__((ext_vector_type(4))) short bf16x4;
typedef __attribute__((ext_vector_type(4))) float f32x4;

__device__ __forceinline__ float bf2f(u16 u) {
  union { unsigned int i; float f; } v; v.i = ((unsigned int)u) << 16; return v.f;
}
__device__ __forceinline__ u16 f2bf(float f) {
  union { float f; unsigned int i; } v; v.f = f;
  unsigned int r = v.i + 0x7fffu + ((v.i >> 16) & 1u);  // RNE
  return (u16)(r >> 16);
}

#define NB 8
#define NC 256
#define NCQ 128
#define NN 4096
#define LOG2E 1.4426950408889634f

// nonzero if any of the first ns even-index u16 samples has exponent >= 0x90:
// impossible for genuine bf16 inputs here, ~44%/sample for f32 mantissa halves.
__device__ __forceinline__ int scan_bad(const u16* p, int ns, int tid) {
  int bad = 0;
  for (int i = tid; i < ns; i += 256) {
    const int e = (p[2 * i] >> 7) & 0xff;
    bad |= (e >= 0x90) ? 1 : 0;
  }
  return bad;
}

__device__ __forceinline__ bf16x8 load8(const u16* pb, const float* pf,
                                        size_t off, bool f) {
  if (!f) return *(const bf16x8*)(pb + off);
  const float4 a = *(const float4*)(pf + off);
  const float4 b = *(const float4*)(pf + off + 4);
  bf16x8 r;
  r[0] = (short)f2bf(a.x); r[1] = (short)f2bf(a.y);
  r[2] = (short)f2bf(a.z); r[3] = (short)f2bf(a.w);
  r[4] = (short)f2bf(b.x); r[5] = (short)f2bf(b.y);
  r[6] = (short)f2bf(b.z); r[7] = (short)f2bf(b.w);
  return r;
}

// ---------------------------------------------------------------- K0: QKV --
__global__ __launch_bounds__(256, 2) void qkv_kernel(
    const void* xv, const void* Wqv, const void* bqv, const void* Wkv,
    const void* bkv, const void* Wvv, const void* bvv,
    u16* __restrict__ q2T, u16* __restrict__ kT, u16* __restrict__ vout) {
  __shared__ __align__(16) u16 xT[64][264];
  __shared__ int fl[8];
  const int tid = threadIdx.x;
  const int bid = blockIdx.x;
  const int b = bid & 7, n0 = (bid >> 3) << 6;

  if (tid < 8) fl[tid] = 0;
  __syncthreads();
  if (scan_bad((const u16*)xv, 256, tid)) fl[0] = 1;
  if (scan_bad((const u16*)Wqv, 64, tid)) fl[1] = 1;
  if (scan_bad((const u16*)Wkv, 64, tid)) fl[2] = 1;
  if (scan_bad((const u16*)Wvv, 64, tid)) fl[3] = 1;
  if (scan_bad((const u16*)bqv, 64, tid)) fl[4] = 1;
  if (scan_bad((const u16*)bkv, 64, tid)) fl[5] = 1;
  if (scan_bad((const u16*)bvv, 64, tid)) fl[6] = 1;
  __syncthreads();
  const bool fx = fl[0] != 0;

  {  // stage x[b][c][n0..n0+63] transposed into LDS (thread = c)
    const int c = tid;
    const size_t roff = (size_t)(b * NC + c) * NN + n0;
    if (fx) {
      const float* xp = (const float*)xv + roff;
#pragma unroll
      for (int j = 0; j < 16; ++j) {
        const float4 t = *(const float4*)(xp + j * 4);
        xT[j * 4 + 0][c] = f2bf(t.x); xT[j * 4 + 1][c] = f2bf(t.y);
        xT[j * 4 + 2][c] = f2bf(t.z); xT[j * 4 + 3][c] = f2bf(t.w);
      }
    } else {
      const u16* xp = (const u16*)xv + roff;
#pragma unroll
      for (int j = 0; j < 8; ++j) {
        bf16x8 t = *(const bf16x8*)(xp + j * 8);
#pragma unroll
        for (int e = 0; e < 8; ++e) xT[j * 8 + e][c] = (u16)t[e];
      }
    }
  }
  __syncthreads();

  const int w = tid >> 6, lane = tid & 63, l15 = lane & 15, quad = lane >> 4;
  const u16* Wb; const float* Wf; const u16* Bb; const float* Bf;
  bool fW, fB; int obase = 0; u16* dstT = nullptr; float sc = 1.f;
  if (w == 0) {
    Wb = (const u16*)Wqv; Wf = (const float*)Wqv;
    Bb = (const u16*)bqv; Bf = (const float*)bqv;
    fW = fl[1]; fB = fl[4]; dstT = q2T; sc = LOG2E;
  } else if (w == 1) {
    Wb = (const u16*)Wkv; Wf = (const float*)Wkv;
    Bb = (const u16*)bkv; Bf = (const float*)bkv;
    fW = fl[2]; fB = fl[5]; dstT = kT;
  } else if (w == 2) {
    Wb = (const u16*)Wvv; Wf = (const float*)Wvv;
    Bb = (const u16*)bvv; Bf = (const float*)bvv;
    fW = fl[3]; fB = fl[6];
  } else {
    Wb = (const u16*)Wvv + 32768; Wf = (const float*)Wvv + 32768;
    Bb = (const u16*)bvv + 128;   Bf = (const float*)bvv + 128;
    fW = fl[3]; fB = fl[6]; obase = 128;
  }

  bf16x8 xfr[4][8];  // x B-frags (from LDS)
#pragma unroll
  for (int nt = 0; nt < 4; ++nt) {
    const u16* xp = &xT[nt * 16 + l15][quad * 8];
#pragma unroll
    for (int ks = 0; ks < 8; ++ks) xfr[nt][ks] = *(const bf16x8*)(xp + ks * 32);
  }

  for (int ot = 0; ot < 8; ++ot) {
    bf16x8 wfr[8];  // A-frag: row o = ot*16+l15, k = c
    const size_t wrow = (size_t)(ot * 16 + l15) * 256 + quad * 8;
#pragma unroll
    for (int ks = 0; ks < 8; ++ks) wfr[ks] = load8(Wb, Wf, wrow + ks * 32, fW);
    float bias[4];
    {
      const int boff = ot * 16 + quad * 4;
#pragma unroll
      for (int r = 0; r < 4; ++r)
        bias[r] = fB ? Bf[boff + r] : bf2f(Bb[boff + r]);
    }
#pragma unroll
    for (int nt = 0; nt < 4; ++nt) {
      f32x4 acc = {0.f, 0.f, 0.f, 0.f};
#pragma unroll
      for (int ks = 0; ks < 8; ++ks)
        acc = __builtin_amdgcn_mfma_f32_16x16x32_bf16(wfr[ks], xfr[nt][ks], acc, 0, 0, 0);
      const int n = n0 + nt * 16 + l15;  // D: col=n-local, row=o-local
      if (w < 2) {
        ushort4 st;
        st.x = f2bf((acc[0] + bias[0]) * sc); st.y = f2bf((acc[1] + bias[1]) * sc);
        st.z = f2bf((acc[2] + bias[2]) * sc); st.w = f2bf((acc[3] + bias[3]) * sc);
        *(ushort4*)(dstT + ((size_t)(b * NN + n)) * NCQ + ot * 16 + quad * 4) = st;
      } else {
        const int c = obase + ot * 16 + quad * 4;
#pragma unroll
        for (int r = 0; r < 4; ++r)
          vout[((size_t)(b * NC + c + r)) * NN + n] = f2bf(acc[r] + bias[r]);
      }
    }
  }
}

// ------------------------------------ K1: r[n] = 1 / sum_m exp2(S2[m,n]) --
// grid 256 = 8 b x 32 n-blocks of 128; 512 threads, wave w owns n-strip
// n0 + w*16. Sweep ALL m; q loads identical across the 8 waves (L1 dedup).
// q traffic: 1MB/block x 256 = 256MB (was 512MB). No in-loop barrier.
__global__ __launch_bounds__(512, 1) void stats_kernel(
    const u16* __restrict__ q2T, const u16* __restrict__ kT,
    float* __restrict__ rbuf) {
  const int bid = blockIdx.x;
  const int b = bid & 7, n0 = (bid >> 3) << 7;
  const int tid = threadIdx.x;
  const int w = tid >> 6, lane = tid & 63, l15 = lane & 15, quad = lane >> 4;

  bf16x8 kf[4];  // loop-invariant k B-frags: row n0 + w*16 + l15, k = c
  {
    const u16* kp = kT + ((size_t)(b * NN + n0 + w * 16 + l15)) * NCQ + quad * 8;
#pragma unroll
    for (int ks = 0; ks < 4; ++ks) {
      kf[ks] = *(const bf16x8*)(kp + ks * 32);
      asm volatile("" : "+v"(kf[ks]));  // pin: no remat into the loop
    }
  }

  float Z = 0.f;
  for (int mb = 0; mb < NN; mb += 64) {  // 4-way unrolled m-sweep
    const u16* qp = q2T + ((size_t)(b * NN + mb + l15)) * NCQ + quad * 8;
    bf16x8 af[4][4];
#pragma unroll
    for (int u = 0; u < 4; ++u)
#pragma unroll
      for (int ks = 0; ks < 4; ++ks)
        af[u][ks] = *(const bf16x8*)(qp + (size_t)(u * 16) * NCQ + ks * 32);
#pragma unroll
    for (int u = 0; u < 4; ++u) {
      f32x4 s = {0.f, 0.f, 0.f, 0.f};
#pragma unroll
      for (int ks = 0; ks < 4; ++ks)
        s = __builtin_amdgcn_mfma_f32_16x16x32_bf16(af[u][ks], kf[ks], s, 0, 0, 0);
      // s[r] = S2[m = mb + u*16 + quad*4 + r][n = n0 + w*16 + l15]
      Z += __builtin_amdgcn_exp2f(s[0]) + __builtin_amdgcn_exp2f(s[1]) +
           __builtin_amdgcn_exp2f(s[2]) + __builtin_amdgcn_exp2f(s[3]);
    }
  }
  // collapse the quad (m) dimension; lanes with equal l15 then agree
  Z += __shfl_xor(Z, 16, 64);
  Z += __shfl_xor(Z, 32, 64);
  if (lane < 16) rbuf[b * NN + n0 + w * 16 + l15] = 1.0f / Z;
}

// -------------------------------------------- K2: v[c][n] *= r[n] in place --
__global__ __launch_bounds__(256, 4) void scale_kernel(
    u16* __restrict__ vr, const float* __restrict__ rbuf) {
  const int flat = (blockIdx.x * 256 + threadIdx.x) * 8;
  const int n = flat & (NN - 1);
  const int b = flat >> 20;
  const float4 r0 = *(const float4*)(rbuf + (b << 12) + n);
  const float4 r1 = *(const float4*)(rbuf + (b << 12) + n + 4);
  const ushort4 a0 = *(const ushort4*)(vr + flat);
  const ushort4 a1 = *(const ushort4*)(vr + flat + 4);
  ushort4 s0, s1;
  s0.x = f2bf(bf2f(a0.x) * r0.x); s0.y = f2bf(bf2f(a0.y) * r0.y);
  s0.z = f2bf(bf2f(a0.z) * r0.z); s0.w = f2bf(bf2f(a0.w) * r0.w);
  s1.x = f2bf(bf2f(a1.x) * r1.x); s1.y = f2bf(bf2f(a1.y) * r1.y);
  s1.z = f2bf(bf2f(a1.z) * r1.z); s1.w = f2bf(bf2f(a1.w) * r1.w);
  *(ushort4*)(vr + flat) = s0;
  *(ushort4*)(vr + flat + 4) = s1;
}

// ------------ K3: E' = exp2(S2) recompute, O = E'.vr^T, y = g*O + x --------
// grid 256 = 8 b x 32 m-blocks of 128; 512 threads = 8 waves. Full 256-c
// per block (no ch split -> S computed once). Wave w: S-phase role
// (mh, nq) = (w>>2, w&3): 4 m-groups of its 64-m half x its 16-n strip;
// PV-phase role: 32-c strip w*32. k+v traffic: 3MB/block x 256 = 768MB
// (was 2.0GB); all 32 blocks/XCD share the same b -> same 4MB k/v/q set.
__global__ __launch_bounds__(512, 1) void out_kernel(
    const u16* __restrict__ q2T, const u16* __restrict__ kT,
    const u16* __restrict__ vr,
    const void* xv, const void* gv,
    const void* bqv, const void* bkv, const void* bvv,
    void* outv) {
  __shared__ __align__(16) u16 et[2][8][16][68];  // [buf][m-grp][m16][n64+pad]
  __shared__ int fl[2];
  const int tid = threadIdx.x;
  if (tid < 2) fl[tid] = 0;
  __syncthreads();
  if (scan_bad((const u16*)xv, 256, tid)) fl[0] = 1;
  if (scan_bad((const u16*)bqv, 64, tid) | scan_bad((const u16*)bkv, 64, tid) |
      scan_bad((const u16*)bvv, 64, tid)) fl[1] = 1;

  const int bid = blockIdx.x;
  const int b = bid & 7;
  const int m0 = (bid >> 3) << 7;
  const int w = tid >> 6, lane = tid & 63, l15 = lane & 15, quad = lane >> 4;
  const int mh = w >> 2, nq = w & 3;

  bf16x8 qf[4][4];  // loop-invariant q B-frags: row m0+mh*64+mg*16+l15, k = c
  {
    const u16* qp = q2T + ((size_t)(b * NN + m0 + mh * 64 + l15)) * NCQ + quad * 8;
#pragma unroll
    for (int mg = 0; mg < 4; ++mg)
#pragma unroll
      for (int ks = 0; ks < 4; ++ks) {
        qf[mg][ks] = *(const bf16x8*)(qp + (size_t)(mg * 16) * NCQ + ks * 32);
        asm volatile("" : "+v"(qf[mg][ks]));  // pin: no remat into the loop
      }
  }
  __syncthreads();
  const bool fx = fl[0] != 0, fg = fl[1] != 0;

  f32x4 acc[16];  // acc[mg*2+ct]: m=m0+mg*16+quad*4+r, c=w*32+ct*16+l15
#pragma unroll
  for (int i = 0; i < 16; ++i) acc[i] = (f32x4){0.f, 0.f, 0.f, 0.f};

  const u16* kb = kT + ((size_t)(b * NN + nq * 16 + l15)) * NCQ + quad * 8;
  const u16* vb = vr + ((size_t)(b * NC + w * 32 + l15)) * NN + quad * 8;

  for (int n0 = 0; n0 < NN; n0 += 64) {
    const int pp = (n0 >> 6) & 1;
    // ---- 8 independent global loads, issued together ----
    bf16x8 kf[4], vf[4];
#pragma unroll
    for (int ks = 0; ks < 4; ++ks)
      kf[ks] = *(const bf16x8*)(kb + (size_t)n0 * NCQ + ks * 32);
#pragma unroll
    for (int ct = 0; ct < 2; ++ct)
#pragma unroll
      for (int ns = 0; ns < 2; ++ns)
        vf[ct * 2 + ns] =
            *(const bf16x8*)(vb + (size_t)(ct * 16) * NN + n0 + ns * 32);
    // ---- S phase: my 64-m half x my 16-n strip; q frags from VGPRs ----
#pragma unroll
    for (int mg = 0; mg < 4; ++mg) {
      f32x4 s = {0.f, 0.f, 0.f, 0.f};
#pragma unroll
      for (int ks = 0; ks < 4; ++ks)
        s = __builtin_amdgcn_mfma_f32_16x16x32_bf16(kf[ks], qf[mg][ks], s, 0, 0, 0);
      // s[r] = S2[m = m0+mh*64+mg*16+l15][n = n0 + nq*16 + quad*4 + r]
      bf16x4 ev;
      ev[0] = (short)f2bf(__builtin_amdgcn_exp2f(s[0]));
      ev[1] = (short)f2bf(__builtin_amdgcn_exp2f(s[1]));
      ev[2] = (short)f2bf(__builtin_amdgcn_exp2f(s[2]));
      ev[3] = (short)f2bf(__builtin_amdgcn_exp2f(s[3]));
      *(bf16x4*)(&et[pp][mh * 4 + mg][l15][nq * 16 + quad * 4]) = ev;
    }
    __syncthreads();
    // ---- PV phase: all 8 m-groups x my 32-c strip ----
#pragma unroll
    for (int mg = 0; mg < 8; ++mg)
#pragma unroll
      for (int ns = 0; ns < 2; ++ns) {
        const bf16x8 af = *(const bf16x8*)(&et[pp][mg][l15][ns * 32 + quad * 8]);
#pragma unroll
        for (int ct = 0; ct < 2; ++ct)
          acc[mg * 2 + ct] = __builtin_amdgcn_mfma_f32_16x16x32_bf16(
              af, vf[ct * 2 + ns], acc[mg * 2 + ct], 0, 0, 0);
      }
    // double-buffered et: next iter writes the other buffer, no 2nd barrier
  }

  const float g = fg ? ((const float*)gv)[0] : bf2f(((const u16*)gv)[0]);
#pragma unroll
  for (int mg = 0; mg < 8; ++mg)
#pragma unroll
    for (int ct = 0; ct < 2; ++ct) {
      const int c = w * 32 + ct * 16 + l15;                      // D col = c
      const int m = m0 + mg * 16 + quad * 4;                     // D row = m
      const size_t base = ((size_t)(b * NC + c)) * NN + m;
      const f32x4 a = acc[mg * 2 + ct];
      if (fx) {
        const float4 xl = *(const float4*)((const float*)xv + base);
        float4 st;
        st.x = g * a[0] + xl.x; st.y = g * a[1] + xl.y;
        st.z = g * a[2] + xl.z; st.w = g * a[3] + xl.w;
        *(float4*)((float*)outv + base) = st;
      } else {
        const ushort4 xl = *(const ushort4*)((const u16*)xv + base);
        ushort4 st;
        st.x = f2bf(g * a[0] + bf2f(xl.x));
        st.y = f2bf(g * a[1] + bf2f(xl.y));
        st.z = f2bf(g * a[2] + bf2f(xl.z));
        st.w = f2bf(g * a[3] + bf2f(xl.w));
        *(ushort4*)((u16*)outv + base) = st;
      }
    }
}

// ---------------------------------------------------------------------------
extern "C" void kernel_launch(void* const* d_in, const int* in_sizes, int n_in,
                              void* d_out, int out_size, void* d_ws, size_t ws_size,
                              hipStream_t stream) {
  // ws: q2 8,388,608 | k 8,388,608 | v 16,777,216 = 32 MiB; r -> tail or d_out
  const size_t NEED = 33554432u;
  if (ws_size < NEED) return;

  char* ws = (char*)d_ws;
  u16* q2 = (u16*)(ws);
  u16* kk = (u16*)(ws + 8388608);
  u16* vv = (u16*)(ws + 16777216);
  float* rbuf = (ws_size >= NEED + 131072u) ? (float*)(ws + NEED) : (float*)d_out;

  qkv_kernel<<<512, 256, 0, stream>>>(d_in[0], d_in[1], d_in[2], d_in[3],
                                      d_in[4], d_in[5], d_in[6], q2, kk, vv);
  stats_kernel<<<256, 512, 0, stream>>>(q2, kk, rbuf);
  scale_kernel<<<4096, 256, 0, stream>>>(vv, rbuf);
  out_kernel<<<256, 512, 0, stream>>>(q2, kk, vv, d_in[0], d_in[7],
                                      d_in[2], d_in[4], d_in[6], d_out);
}

// Round 3
// 438.435 us; speedup vs baseline: 1.1998x; 1.1998x over previous
//
#include <hip/hip_runtime.h>

// ---------------------------------------------------------------------------
// SelfAttention: B=8, C=256, CQ=128, N=4096
//   q = Wq x + bq ; k = Wk x + bk ; v = Wv x + bv   (per-pixel 1x1 conv)
//   S[b,m,n] = q_m.k_n ; A = softmax over m (per column n)
//   O[b,c,m] = sum_n v[c,n] A[m,n] ; y = gamma*O + x
//
// Inputs may be f32 or bf16 (runtime-detected). ws = 32 MiB:
//   K0 qkv : project. q2T[b][m][c]=q*log2e, kT[b][n][c], v[b][c][n] (bf16)
//   K1 stats: r[b][n] = 1 / sum_m exp2(S2[m,n])
//   K2 scale: v *= r[n] in place
//   K3 out : S-recompute -> exp2 -> LDS C->A flip -> PV MFMA -> y = g*O + x
//
// R9 post-mortem: stats 90->241us (VGPR_Count=32: compiler SERIALIZED the
// 16 unrolled loads/iter, 9000 cyc/iter = 16 x ~550cyc sequential; grid 256
// = 1 block/CU removed cross-block overlap). out improved only ~20% from a
// 2.6x traffic cut -> NOT fabric-BW-bound. Both kernels are load-LATENCY
// bound in a 2-phase lockstep loop (m233 regime). R8's pinned qf (64 regs)
// never fit VGPR_Count=64 -> spilled, why R8==R7.
// R10: revert to R7/R8 geometry; attack latency with T14 register prefetch:
//   out : q frags from LDS (no 64-reg pin); kf double-buffered in regs
//         (consumed at S-start; prefetched one 64-tile ahead); vf issued at
//         loop top (consumed after S+barrier = already hidden). Two tiles
//         per body -> compile-time et/kf buffer indices.
//   stats: R8 structure (kf pinned 16 regs, wave = m-quarter) + af double-
//         buffered prefetch, manual 2-step body.
// ---------------------------------------------------------------------------

typedef unsigned short u16;
typedef __attribute__((ext_vector_type(8))) short bf16x8;
typedef __attribute__((ext_vector_type(4))) short bf16x4;
typedef __attribute__((ext_vector_type(4))) float f32x4;

__device__ __forceinline__ float bf2f(u16 u) {
  union { unsigned int i; float f; } v; v.i = ((unsigned int)u) << 16; return v.f;
}
__device__ __forceinline__ u16 f2bf(float f) {
  union { float f; unsigned int i; } v; v.f = f;
  unsigned int r = v.i + 0x7fffu + ((v.i >> 16) & 1u);  // RNE
  return (u16)(r >> 16);
}

#define NB 8
#define NC 256
#define NCQ 128
#define NN 4096
#define LOG2E 1.4426950408889634f

// nonzero if any of the first ns even-index u16 samples has exponent >= 0x90:
// impossible for genuine bf16 inputs here, ~44%/sample for f32 mantissa halves.
__device__ __forceinline__ int scan_bad(const u16* p, int ns, int tid) {
  int bad = 0;
  for (int i = tid; i < ns; i += 256) {
    const int e = (p[2 * i] >> 7) & 0xff;
    bad |= (e >= 0x90) ? 1 : 0;
  }
  return bad;
}

__device__ __forceinline__ bf16x8 load8(const u16* pb, const float* pf,
                                        size_t off, bool f) {
  if (!f) return *(const bf16x8*)(pb + off);
  const float4 a = *(const float4*)(pf + off);
  const float4 b = *(const float4*)(pf + off + 4);
  bf16x8 r;
  r[0] = (short)f2bf(a.x); r[1] = (short)f2bf(a.y);
  r[2] = (short)f2bf(a.z); r[3] = (short)f2bf(a.w);
  r[4] = (short)f2bf(b.x); r[5] = (short)f2bf(b.y);
  r[6] = (short)f2bf(b.z); r[7] = (short)f2bf(b.w);
  return r;
}

// ---------------------------------------------------------------- K0: QKV --
__global__ __launch_bounds__(256, 2) void qkv_kernel(
    const void* xv, const void* Wqv, const void* bqv, const void* Wkv,
    const void* bkv, const void* Wvv, const void* bvv,
    u16* __restrict__ q2T, u16* __restrict__ kT, u16* __restrict__ vout) {
  __shared__ __align__(16) u16 xT[64][264];
  __shared__ int fl[8];
  const int tid = threadIdx.x;
  const int bid = blockIdx.x;
  const int b = bid & 7, n0 = (bid >> 3) << 6;

  if (tid < 8) fl[tid] = 0;
  __syncthreads();
  if (scan_bad((const u16*)xv, 256, tid)) fl[0] = 1;
  if (scan_bad((const u16*)Wqv, 64, tid)) fl[1] = 1;
  if (scan_bad((const u16*)Wkv, 64, tid)) fl[2] = 1;
  if (scan_bad((const u16*)Wvv, 64, tid)) fl[3] = 1;
  if (scan_bad((const u16*)bqv, 64, tid)) fl[4] = 1;
  if (scan_bad((const u16*)bkv, 64, tid)) fl[5] = 1;
  if (scan_bad((const u16*)bvv, 64, tid)) fl[6] = 1;
  __syncthreads();
  const bool fx = fl[0] != 0;

  {  // stage x[b][c][n0..n0+63] transposed into LDS (thread = c)
    const int c = tid;
    const size_t roff = (size_t)(b * NC + c) * NN + n0;
    if (fx) {
      const float* xp = (const float*)xv + roff;
#pragma unroll
      for (int j = 0; j < 16; ++j) {
        const float4 t = *(const float4*)(xp + j * 4);
        xT[j * 4 + 0][c] = f2bf(t.x); xT[j * 4 + 1][c] = f2bf(t.y);
        xT[j * 4 + 2][c] = f2bf(t.z); xT[j * 4 + 3][c] = f2bf(t.w);
      }
    } else {
      const u16* xp = (const u16*)xv + roff;
#pragma unroll
      for (int j = 0; j < 8; ++j) {
        bf16x8 t = *(const bf16x8*)(xp + j * 8);
#pragma unroll
        for (int e = 0; e < 8; ++e) xT[j * 8 + e][c] = (u16)t[e];
      }
    }
  }
  __syncthreads();

  const int w = tid >> 6, lane = tid & 63, l15 = lane & 15, quad = lane >> 4;
  const u16* Wb; const float* Wf; const u16* Bb; const float* Bf;
  bool fW, fB; int obase = 0; u16* dstT = nullptr; float sc = 1.f;
  if (w == 0) {
    Wb = (const u16*)Wqv; Wf = (const float*)Wqv;
    Bb = (const u16*)bqv; Bf = (const float*)bqv;
    fW = fl[1]; fB = fl[4]; dstT = q2T; sc = LOG2E;
  } else if (w == 1) {
    Wb = (const u16*)Wkv; Wf = (const float*)Wkv;
    Bb = (const u16*)bkv; Bf = (const float*)bkv;
    fW = fl[2]; fB = fl[5]; dstT = kT;
  } else if (w == 2) {
    Wb = (const u16*)Wvv; Wf = (const float*)Wvv;
    Bb = (const u16*)bvv; Bf = (const float*)bvv;
    fW = fl[3]; fB = fl[6];
  } else {
    Wb = (const u16*)Wvv + 32768; Wf = (const float*)Wvv + 32768;
    Bb = (const u16*)bvv + 128;   Bf = (const float*)bvv + 128;
    fW = fl[3]; fB = fl[6]; obase = 128;
  }

  bf16x8 xfr[4][8];  // x B-frags (from LDS)
#pragma unroll
  for (int nt = 0; nt < 4; ++nt) {
    const u16* xp = &xT[nt * 16 + l15][quad * 8];
#pragma unroll
    for (int ks = 0; ks < 8; ++ks) xfr[nt][ks] = *(const bf16x8*)(xp + ks * 32);
  }

  for (int ot = 0; ot < 8; ++ot) {
    bf16x8 wfr[8];  // A-frag: row o = ot*16+l15, k = c
    const size_t wrow = (size_t)(ot * 16 + l15) * 256 + quad * 8;
#pragma unroll
    for (int ks = 0; ks < 8; ++ks) wfr[ks] = load8(Wb, Wf, wrow + ks * 32, fW);
    float bias[4];
    {
      const int boff = ot * 16 + quad * 4;
#pragma unroll
      for (int r = 0; r < 4; ++r)
        bias[r] = fB ? Bf[boff + r] : bf2f(Bb[boff + r]);
    }
#pragma unroll
    for (int nt = 0; nt < 4; ++nt) {
      f32x4 acc = {0.f, 0.f, 0.f, 0.f};
#pragma unroll
      for (int ks = 0; ks < 8; ++ks)
        acc = __builtin_amdgcn_mfma_f32_16x16x32_bf16(wfr[ks], xfr[nt][ks], acc, 0, 0, 0);
      const int n = n0 + nt * 16 + l15;  // D: col=n-local, row=o-local
      if (w < 2) {
        ushort4 st;
        st.x = f2bf((acc[0] + bias[0]) * sc); st.y = f2bf((acc[1] + bias[1]) * sc);
        st.z = f2bf((acc[2] + bias[2]) * sc); st.w = f2bf((acc[3] + bias[3]) * sc);
        *(ushort4*)(dstT + ((size_t)(b * NN + n)) * NCQ + ot * 16 + quad * 4) = st;
      } else {
        const int c = obase + ot * 16 + quad * 4;
#pragma unroll
        for (int r = 0; r < 4; ++r)
          vout[((size_t)(b * NC + c + r)) * NN + n] = f2bf(acc[r] + bias[r]);
      }
    }
  }
}

// ------------------------------------ K1: r[n] = 1 / sum_m exp2(S2[m,n]) --
// grid 512 = 8 b x 64 n-blocks; wave w covers m in [w*1024, (w+1)*1024).
// kf pinned (16 regs, fits); af double-buffered register prefetch so the
// 4 q loads for iter i+1 are in flight during iter i's 16 MFMA + exp2.
__global__ __launch_bounds__(256, 2) void stats_kernel(
    const u16* __restrict__ q2T, const u16* __restrict__ kT,
    float* __restrict__ rbuf) {
  __shared__ float zbuf[4][64];
  const int bid = blockIdx.x;
  const int b = bid & 7, n0 = (bid >> 3) << 6;
  const int tid = threadIdx.x;
  const int w = tid >> 6, lane = tid & 63, l15 = lane & 15, quad = lane >> 4;

  bf16x8 kf[4][4];  // loop-invariant k B-frags: row n0+nt*16+l15, k = c
  {
    const u16* kp = kT + ((size_t)(b * NN + n0 + l15)) * NCQ + quad * 8;
#pragma unroll
    for (int nt = 0; nt < 4; ++nt)
#pragma unroll
      for (int ks = 0; ks < 4; ++ks) {
        kf[nt][ks] = *(const bf16x8*)(kp + (size_t)(nt * 16) * NCQ + ks * 32);
        asm volatile("" : "+v"(kf[nt][ks]));  // pin: no remat into the loop
      }
  }

  const u16* qbase = q2T + ((size_t)(b * NN + w * 1024 + l15)) * NCQ + quad * 8;
  float Z[4] = {0.f, 0.f, 0.f, 0.f};
  bf16x8 afA[4], afB[4];
#pragma unroll
  for (int ks = 0; ks < 4; ++ks) afA[ks] = *(const bf16x8*)(qbase + ks * 32);

  for (int it = 0; it < 64; it += 2) {
    // prefetch it+1 into afB, then compute it with afA
    {
      const u16* qp = qbase + (size_t)((it + 1) * 16) * NCQ;
#pragma unroll
      for (int ks = 0; ks < 4; ++ks) afB[ks] = *(const bf16x8*)(qp + ks * 32);
    }
#pragma unroll
    for (int nt = 0; nt < 4; ++nt) {
      f32x4 acc = {0.f, 0.f, 0.f, 0.f};
#pragma unroll
      for (int ks = 0; ks < 4; ++ks)
        acc = __builtin_amdgcn_mfma_f32_16x16x32_bf16(afA[ks], kf[nt][ks], acc, 0, 0, 0);
      Z[nt] += __builtin_amdgcn_exp2f(acc[0]) + __builtin_amdgcn_exp2f(acc[1]) +
               __builtin_amdgcn_exp2f(acc[2]) + __builtin_amdgcn_exp2f(acc[3]);
    }
    // prefetch it+2 into afA (wrap at the end; extra values unused), compute it+1
    {
      const int it2 = (it + 2) & 63;
      const u16* qp = qbase + (size_t)(it2 * 16) * NCQ;
#pragma unroll
      for (int ks = 0; ks < 4; ++ks) afA[ks] = *(const bf16x8*)(qp + ks * 32);
    }
#pragma unroll
    for (int nt = 0; nt < 4; ++nt) {
      f32x4 acc = {0.f, 0.f, 0.f, 0.f};
#pragma unroll
      for (int ks = 0; ks < 4; ++ks)
        acc = __builtin_amdgcn_mfma_f32_16x16x32_bf16(afB[ks], kf[nt][ks], acc, 0, 0, 0);
      Z[nt] += __builtin_amdgcn_exp2f(acc[0]) + __builtin_amdgcn_exp2f(acc[1]) +
               __builtin_amdgcn_exp2f(acc[2]) + __builtin_amdgcn_exp2f(acc[3]);
    }
  }
#pragma unroll
  for (int nt = 0; nt < 4; ++nt) {
    float z = Z[nt];
    z += __shfl_xor(z, 16, 64);
    z += __shfl_xor(z, 32, 64);
    Z[nt] = z;
  }
  if (lane < 16) {
#pragma unroll
    for (int nt = 0; nt < 4; ++nt) zbuf[w][nt * 16 + lane] = Z[nt];
  }
  __syncthreads();
  if (tid < 64) {
    const float z = zbuf[0][tid] + zbuf[1][tid] + zbuf[2][tid] + zbuf[3][tid];
    rbuf[b * NN + n0 + tid] = 1.0f / z;
  }
}

// -------------------------------------------- K2: v[c][n] *= r[n] in place --
__global__ __launch_bounds__(256, 4) void scale_kernel(
    u16* __restrict__ vr, const float* __restrict__ rbuf) {
  const int flat = (blockIdx.x * 256 + threadIdx.x) * 8;
  const int n = flat & (NN - 1);
  const int b = flat >> 20;
  const float4 r0 = *(const float4*)(rbuf + (b << 12) + n);
  const float4 r1 = *(const float4*)(rbuf + (b << 12) + n + 4);
  const ushort4 a0 = *(const ushort4*)(vr + flat);
  const ushort4 a1 = *(const ushort4*)(vr + flat + 4);
  ushort4 s0, s1;
  s0.x = f2bf(bf2f(a0.x) * r0.x); s0.y = f2bf(bf2f(a0.y) * r0.y);
  s0.z = f2bf(bf2f(a0.z) * r0.z); s0.w = f2bf(bf2f(a0.w) * r0.w);
  s1.x = f2bf(bf2f(a1.x) * r1.x); s1.y = f2bf(bf2f(a1.y) * r1.y);
  s1.z = f2bf(bf2f(a1.z) * r1.z); s1.w = f2bf(bf2f(a1.w) * r1.w);
  *(ushort4*)(vr + flat) = s0;
  *(ushort4*)(vr + flat + 4) = s1;
}

// ------------ K3: E' = exp2(S2) recompute, O = E'.vr^T, y = g*O + x --------
// grid 1024 = 8 b x 64 m-blocks x 2 c-halves. q-tile (64m x 128c) in LDS
// (no 64-reg pin -- R8's spilled). kf double-buffered register prefetch:
// tile n0's kf loaded one 64-tile ahead, so the S-phase never waits on L2.
// vf issued at body top, consumed after S+barrier (latency already hidden).
// Two 64-tiles per body -> et/kf buffer indices are compile-time constants.
__global__ __launch_bounds__(256, 4) void out_kernel(
    const u16* __restrict__ q2T, const u16* __restrict__ kT,
    const u16* __restrict__ vr,
    const void* xv, const void* gv,
    const void* bqv, const void* bkv, const void* bvv,
    void* outv) {
  __shared__ __align__(16) u16 qs[64][136];
  __shared__ __align__(16) u16 et[2][4][16][68];
  __shared__ int fl[2];
  const int tid = threadIdx.x;
  if (tid < 2) fl[tid] = 0;
  __syncthreads();
  if (scan_bad((const u16*)xv, 256, tid)) fl[0] = 1;
  if (scan_bad((const u16*)bqv, 64, tid) | scan_bad((const u16*)bkv, 64, tid) |
      scan_bad((const u16*)bvv, 64, tid)) fl[1] = 1;

  const int bid = blockIdx.x;
  const int b = bid & 7;
  const int r7 = bid >> 3;
  const int ch = r7 & 1;
  const int m0 = (r7 >> 1) << 6;
  const int w = tid >> 6, lane = tid & 63, l15 = lane & 15, quad = lane >> 4;

  {  // stage q2T[b][m0..m0+63][0..128) -> qs; thread t: row t>>2, 32 c
    const int mm = tid >> 2, ck = (tid & 3) * 32;
    const u16* src = q2T + ((size_t)(b * NN + m0 + mm)) * NCQ + ck;
#pragma unroll
    for (int j = 0; j < 4; ++j)
      *(bf16x8*)(&qs[mm][ck + j * 8]) = *(const bf16x8*)(src + j * 8);
  }
  __syncthreads();
  const bool fx = fl[0] != 0, fg = fl[1] != 0;

  f32x4 acc[8];  // acc[mg*2+ct]: m=m0+mg*16+quad*4+r, c=ch*128+w*32+ct*16+l15
#pragma unroll
  for (int i = 0; i < 8; ++i) acc[i] = (f32x4){0.f, 0.f, 0.f, 0.f};

  const u16* kb = kT + ((size_t)(b * NN + w * 16 + l15)) * NCQ + quad * 8;
  const u16* vb = vr + ((size_t)(b * NC + ch * 128 + w * 32 + l15)) * NN + quad * 8;

  bf16x8 kfA[4], kfB[4];
#pragma unroll
  for (int ks = 0; ks < 4; ++ks)  // kf for tile n0 = 0
    kfA[ks] = *(const bf16x8*)(kb + ks * 32);

  for (int n0 = 0; n0 < NN; n0 += 128) {
    // ================= step A: tile n0 (kfA, et[0]); prefetch kfB@n0+64 ====
    {
      bf16x8 vf[4];
#pragma unroll
      for (int ct = 0; ct < 2; ++ct)
#pragma unroll
        for (int ns = 0; ns < 2; ++ns)
          vf[ct * 2 + ns] =
              *(const bf16x8*)(vb + (size_t)(ct * 16) * NN + n0 + ns * 32);
#pragma unroll
      for (int ks = 0; ks < 4; ++ks)
        kfB[ks] = *(const bf16x8*)(kb + (size_t)(n0 + 64) * NCQ + ks * 32);
      // ---- S phase: q frags from LDS, k from kfA (in flight since last body)
#pragma unroll
      for (int mg = 0; mg < 4; ++mg) {
        f32x4 s = {0.f, 0.f, 0.f, 0.f};
#pragma unroll
        for (int ks = 0; ks < 4; ++ks) {
          const bf16x8 qfr =
              *(const bf16x8*)(&qs[mg * 16 + l15][quad * 8 + ks * 32]);
          s = __builtin_amdgcn_mfma_f32_16x16x32_bf16(kfA[ks], qfr, s, 0, 0, 0);
        }
        // s[r] = S2[m = m0+mg*16+l15][n = n0 + w*16 + quad*4 + r]
        bf16x4 ev;
        ev[0] = (short)f2bf(__builtin_amdgcn_exp2f(s[0]));
        ev[1] = (short)f2bf(__builtin_amdgcn_exp2f(s[1]));
        ev[2] = (short)f2bf(__builtin_amdgcn_exp2f(s[2]));
        ev[3] = (short)f2bf(__builtin_amdgcn_exp2f(s[3]));
        *(bf16x4*)(&et[0][mg][l15][w * 16 + quad * 4]) = ev;
      }
      __syncthreads();
      // ---- PV phase ----
#pragma unroll
      for (int mg = 0; mg < 4; ++mg)
#pragma unroll
        for (int ns = 0; ns < 2; ++ns) {
          const bf16x8 af = *(const bf16x8*)(&et[0][mg][l15][ns * 32 + quad * 8]);
#pragma unroll
          for (int ct = 0; ct < 2; ++ct)
            acc[mg * 2 + ct] = __builtin_amdgcn_mfma_f32_16x16x32_bf16(
                af, vf[ct * 2 + ns], acc[mg * 2 + ct], 0, 0, 0);
        }
    }
    // ================= step B: tile n0+64 (kfB, et[1]); prefetch kfA =======
    {
      const int n1 = n0 + 64;
      bf16x8 vf[4];
#pragma unroll
      for (int ct = 0; ct < 2; ++ct)
#pragma unroll
        for (int ns = 0; ns < 2; ++ns)
          vf[ct * 2 + ns] =
              *(const bf16x8*)(vb + (size_t)(ct * 16) * NN + n1 + ns * 32);
      {
        const int n2 = (n0 + 128) & (NN - 1);  // wrap at end; values unused
#pragma unroll
        for (int ks = 0; ks < 4; ++ks)
          kfA[ks] = *(const bf16x8*)(kb + (size_t)n2 * NCQ + ks * 32);
      }
#pragma unroll
      for (int mg = 0; mg < 4; ++mg) {
        f32x4 s = {0.f, 0.f, 0.f, 0.f};
#pragma unroll
        for (int ks = 0; ks < 4; ++ks) {
          const bf16x8 qfr =
              *(const bf16x8*)(&qs[mg * 16 + l15][quad * 8 + ks * 32]);
          s = __builtin_amdgcn_mfma_f32_16x16x32_bf16(kfB[ks], qfr, s, 0, 0, 0);
        }
        bf16x4 ev;
        ev[0] = (short)f2bf(__builtin_amdgcn_exp2f(s[0]));
        ev[1] = (short)f2bf(__builtin_amdgcn_exp2f(s[1]));
        ev[2] = (short)f2bf(__builtin_amdgcn_exp2f(s[2]));
        ev[3] = (short)f2bf(__builtin_amdgcn_exp2f(s[3]));
        *(bf16x4*)(&et[1][mg][l15][w * 16 + quad * 4]) = ev;
      }
      __syncthreads();
#pragma unroll
      for (int mg = 0; mg < 4; ++mg)
#pragma unroll
        for (int ns = 0; ns < 2; ++ns) {
          const bf16x8 af = *(const bf16x8*)(&et[1][mg][l15][ns * 32 + quad * 8]);
#pragma unroll
          for (int ct = 0; ct < 2; ++ct)
            acc[mg * 2 + ct] = __builtin_amdgcn_mfma_f32_16x16x32_bf16(
                af, vf[ct * 2 + ns], acc[mg * 2 + ct], 0, 0, 0);
        }
    }
  }

  const float g = fg ? ((const float*)gv)[0] : bf2f(((const u16*)gv)[0]);
#pragma unroll
  for (int mg = 0; mg < 4; ++mg)
#pragma unroll
    for (int ct = 0; ct < 2; ++ct) {
      const int c = ch * 128 + w * 32 + ct * 16 + l15;           // D col = c
      const int m = m0 + mg * 16 + quad * 4;                     // D row = m
      const size_t base = ((size_t)(b * NC + c)) * NN + m;
      const f32x4 a = acc[mg * 2 + ct];
      if (fx) {
        const float4 xl = *(const float4*)((const float*)xv + base);
        float4 st;
        st.x = g * a[0] + xl.x; st.y = g * a[1] + xl.y;
        st.z = g * a[2] + xl.z; st.w = g * a[3] + xl.w;
        *(float4*)((float*)outv + base) = st;
      } else {
        const ushort4 xl = *(const ushort4*)((const u16*)xv + base);
        ushort4 st;
        st.x = f2bf(g * a[0] + bf2f(xl.x));
        st.y = f2bf(g * a[1] + bf2f(xl.y));
        st.z = f2bf(g * a[2] + bf2f(xl.z));
        st.w = f2bf(g * a[3] + bf2f(xl.w));
        *(ushort4*)((u16*)outv + base) = st;
      }
    }
}

// ---------------------------------------------------------------------------
extern "C" void kernel_launch(void* const* d_in, const int* in_sizes, int n_in,
                              void* d_out, int out_size, void* d_ws, size_t ws_size,
                              hipStream_t stream) {
  // ws: q2 8,388,608 | k 8,388,608 | v 16,777,216 = 32 MiB; r -> tail or d_out
  const size_t NEED = 33554432u;
  if (ws_size < NEED) return;

  char* ws = (char*)d_ws;
  u16* q2 = (u16*)(ws);
  u16* kk = (u16*)(ws + 8388608);
  u16* vv = (u16*)(ws + 16777216);
  float* rbuf = (ws_size >= NEED + 131072u) ? (float*)(ws + NEED) : (float*)d_out;

  qkv_kernel<<<512, 256, 0, stream>>>(d_in[0], d_in[1], d_in[2], d_in[3],
                                      d_in[4], d_in[5], d_in[6], q2, kk, vv);
  stats_kernel<<<512, 256, 0, stream>>>(q2, kk, rbuf);
  scale_kernel<<<4096, 256, 0, stream>>>(vv, rbuf);
  out_kernel<<<1024, 256, 0, stream>>>(q2, kk, vv, d_in[0], d_in[7],
                                       d_in[2], d_in[4], d_in[6], d_out);
}

// Round 4
// 434.304 us; speedup vs baseline: 1.2112x; 1.0095x over previous
//
#include <hip/hip_runtime.h>

// ---------------------------------------------------------------------------
// SelfAttention: B=8, C=256, CQ=128, N=4096
//   q = Wq x + bq ; k = Wk x + bk ; v = Wv x + bv   (per-pixel 1x1 conv)
//   S[b,m,n] = q_m.k_n ; A = softmax over m (per column n)
//   O[b,c,m] = sum_n v[c,n] A[m,n] ; y = gamma*O + x
//
// Inputs may be f32 or bf16 (runtime-detected). ws = 32 MiB:
//   K0 qkv : project. q2T[b][m][c]=q*log2e, kT[b][n][c], v[b][c][n] (bf16)
//   K1 stats: r[b][n] = 1 / sum_m exp2(S2[m,n])
//   K2 scale: v *= r[n] in place
//   K3 out : S-recompute -> exp2 -> LDS C->A flip -> PV MFMA -> y = g*O + x
//
// R10 post-mortem: R7/R8/R10 (LDS-q / reg-q+0-conflicts / reg-prefetch) all
// 265-276us. Per-CU-iter budget: LDS 5.0K + MFMA 2.5K + VALU 1.6K = 9.1K cyc
// ~= measured 10.3K -> pipes run SERIALIZED (m233 2-phase-lockstep regime;
// single-piece fixes null, matching R8/R10). The serializer: the dependent
// chain through every barrier: S->exp2->et write->BARRIER->et read->PV->S.
// R11: segment pipelining. Segment t = { S(t) || PV(t-1) } between barriers.
// Same dbuf et + 1 barrier/tile invariant (seg t writes et[t&1], reads
// et[(t-1)&1]; hazards barrier-separated as before). Inside a segment the
// S and PV streams are INDEPENDENT -> MFMA/LDS/VALU overlap instead of
// alternating. Raw lgkmcnt(0)+s_barrier (no vmcnt drain) so the kf(t+1)
// prefetch survives the barrier; vf(t-1) issued at segment top, consumed
// ~600cyc later by PV. VGPR ~ kc16+kn16+vf16+acc32+temps ~= 115 < 128.
// ---------------------------------------------------------------------------

typedef unsigned short u16;
typedef __attribute__((ext_vector_type(8))) short bf16x8;
typedef __attribute__((ext_vector_type(4))) short bf16x4;
typedef __attribute__((ext_vector_type(4))) float f32x4;

__device__ __forceinline__ float bf2f(u16 u) {
  union { unsigned int i; float f; } v; v.i = ((unsigned int)u) << 16; return v.f;
}
__device__ __forceinline__ u16 f2bf(float f) {
  union { float f; unsigned int i; } v; v.f = f;
  unsigned int r = v.i + 0x7fffu + ((v.i >> 16) & 1u);  // RNE
  return (u16)(r >> 16);
}

#define NB 8
#define NC 256
#define NCQ 128
#define NN 4096
#define LOG2E 1.4426950408889634f

// raw workgroup barrier: LDS writes drained, global loads stay in flight.
__device__ __forceinline__ void seg_barrier() {
  asm volatile("s_waitcnt lgkmcnt(0)" ::: "memory");
  __builtin_amdgcn_sched_barrier(0);
  __builtin_amdgcn_s_barrier();
}

// nonzero if any of the first ns even-index u16 samples has exponent >= 0x90:
// impossible for genuine bf16 inputs here, ~44%/sample for f32 mantissa halves.
__device__ __forceinline__ int scan_bad(const u16* p, int ns, int tid) {
  int bad = 0;
  for (int i = tid; i < ns; i += 256) {
    const int e = (p[2 * i] >> 7) & 0xff;
    bad |= (e >= 0x90) ? 1 : 0;
  }
  return bad;
}

__device__ __forceinline__ bf16x8 load8(const u16* pb, const float* pf,
                                        size_t off, bool f) {
  if (!f) return *(const bf16x8*)(pb + off);
  const float4 a = *(const float4*)(pf + off);
  const float4 b = *(const float4*)(pf + off + 4);
  bf16x8 r;
  r[0] = (short)f2bf(a.x); r[1] = (short)f2bf(a.y);
  r[2] = (short)f2bf(a.z); r[3] = (short)f2bf(a.w);
  r[4] = (short)f2bf(b.x); r[5] = (short)f2bf(b.y);
  r[6] = (short)f2bf(b.z); r[7] = (short)f2bf(b.w);
  return r;
}

// ---------------------------------------------------------------- K0: QKV --
__global__ __launch_bounds__(256, 2) void qkv_kernel(
    const void* xv, const void* Wqv, const void* bqv, const void* Wkv,
    const void* bkv, const void* Wvv, const void* bvv,
    u16* __restrict__ q2T, u16* __restrict__ kT, u16* __restrict__ vout) {
  __shared__ __align__(16) u16 xT[64][264];
  __shared__ int fl[8];
  const int tid = threadIdx.x;
  const int bid = blockIdx.x;
  const int b = bid & 7, n0 = (bid >> 3) << 6;

  if (tid < 8) fl[tid] = 0;
  __syncthreads();
  if (scan_bad((const u16*)xv, 256, tid)) fl[0] = 1;
  if (scan_bad((const u16*)Wqv, 64, tid)) fl[1] = 1;
  if (scan_bad((const u16*)Wkv, 64, tid)) fl[2] = 1;
  if (scan_bad((const u16*)Wvv, 64, tid)) fl[3] = 1;
  if (scan_bad((const u16*)bqv, 64, tid)) fl[4] = 1;
  if (scan_bad((const u16*)bkv, 64, tid)) fl[5] = 1;
  if (scan_bad((const u16*)bvv, 64, tid)) fl[6] = 1;
  __syncthreads();
  const bool fx = fl[0] != 0;

  {  // stage x[b][c][n0..n0+63] transposed into LDS (thread = c)
    const int c = tid;
    const size_t roff = (size_t)(b * NC + c) * NN + n0;
    if (fx) {
      const float* xp = (const float*)xv + roff;
#pragma unroll
      for (int j = 0; j < 16; ++j) {
        const float4 t = *(const float4*)(xp + j * 4);
        xT[j * 4 + 0][c] = f2bf(t.x); xT[j * 4 + 1][c] = f2bf(t.y);
        xT[j * 4 + 2][c] = f2bf(t.z); xT[j * 4 + 3][c] = f2bf(t.w);
      }
    } else {
      const u16* xp = (const u16*)xv + roff;
#pragma unroll
      for (int j = 0; j < 8; ++j) {
        bf16x8 t = *(const bf16x8*)(xp + j * 8);
#pragma unroll
        for (int e = 0; e < 8; ++e) xT[j * 8 + e][c] = (u16)t[e];
      }
    }
  }
  __syncthreads();

  const int w = tid >> 6, lane = tid & 63, l15 = lane & 15, quad = lane >> 4;
  const u16* Wb; const float* Wf; const u16* Bb; const float* Bf;
  bool fW, fB; int obase = 0; u16* dstT = nullptr; float sc = 1.f;
  if (w == 0) {
    Wb = (const u16*)Wqv; Wf = (const float*)Wqv;
    Bb = (const u16*)bqv; Bf = (const float*)bqv;
    fW = fl[1]; fB = fl[4]; dstT = q2T; sc = LOG2E;
  } else if (w == 1) {
    Wb = (const u16*)Wkv; Wf = (const float*)Wkv;
    Bb = (const u16*)bkv; Bf = (const float*)bkv;
    fW = fl[2]; fB = fl[5]; dstT = kT;
  } else if (w == 2) {
    Wb = (const u16*)Wvv; Wf = (const float*)Wvv;
    Bb = (const u16*)bvv; Bf = (const float*)bvv;
    fW = fl[3]; fB = fl[6];
  } else {
    Wb = (const u16*)Wvv + 32768; Wf = (const float*)Wvv + 32768;
    Bb = (const u16*)bvv + 128;   Bf = (const float*)bvv + 128;
    fW = fl[3]; fB = fl[6]; obase = 128;
  }

  bf16x8 xfr[4][8];  // x B-frags (from LDS)
#pragma unroll
  for (int nt = 0; nt < 4; ++nt) {
    const u16* xp = &xT[nt * 16 + l15][quad * 8];
#pragma unroll
    for (int ks = 0; ks < 8; ++ks) xfr[nt][ks] = *(const bf16x8*)(xp + ks * 32);
  }

  for (int ot = 0; ot < 8; ++ot) {
    bf16x8 wfr[8];  // A-frag: row o = ot*16+l15, k = c
    const size_t wrow = (size_t)(ot * 16 + l15) * 256 + quad * 8;
#pragma unroll
    for (int ks = 0; ks < 8; ++ks) wfr[ks] = load8(Wb, Wf, wrow + ks * 32, fW);
    float bias[4];
    {
      const int boff = ot * 16 + quad * 4;
#pragma unroll
      for (int r = 0; r < 4; ++r)
        bias[r] = fB ? Bf[boff + r] : bf2f(Bb[boff + r]);
    }
#pragma unroll
    for (int nt = 0; nt < 4; ++nt) {
      f32x4 acc = {0.f, 0.f, 0.f, 0.f};
#pragma unroll
      for (int ks = 0; ks < 8; ++ks)
        acc = __builtin_amdgcn_mfma_f32_16x16x32_bf16(wfr[ks], xfr[nt][ks], acc, 0, 0, 0);
      const int n = n0 + nt * 16 + l15;  // D: col=n-local, row=o-local
      if (w < 2) {
        ushort4 st;
        st.x = f2bf((acc[0] + bias[0]) * sc); st.y = f2bf((acc[1] + bias[1]) * sc);
        st.z = f2bf((acc[2] + bias[2]) * sc); st.w = f2bf((acc[3] + bias[3]) * sc);
        *(ushort4*)(dstT + ((size_t)(b * NN + n)) * NCQ + ot * 16 + quad * 4) = st;
      } else {
        const int c = obase + ot * 16 + quad * 4;
#pragma unroll
        for (int r = 0; r < 4; ++r)
          vout[((size_t)(b * NC + c + r)) * NN + n] = f2bf(acc[r] + bias[r]);
      }
    }
  }
}

// ------------------------------------ K1: r[n] = 1 / sum_m exp2(S2[m,n]) --
// grid 512 = 8 b x 64 n-blocks; wave w covers m in [w*1024, (w+1)*1024).
// kf pinned (16 regs, fits); af double-buffered register prefetch so the
// 4 q loads for iter i+1 are in flight during iter i's 16 MFMA + exp2.
__global__ __launch_bounds__(256, 2) void stats_kernel(
    const u16* __restrict__ q2T, const u16* __restrict__ kT,
    float* __restrict__ rbuf) {
  __shared__ float zbuf[4][64];
  const int bid = blockIdx.x;
  const int b = bid & 7, n0 = (bid >> 3) << 6;
  const int tid = threadIdx.x;
  const int w = tid >> 6, lane = tid & 63, l15 = lane & 15, quad = lane >> 4;

  bf16x8 kf[4][4];  // loop-invariant k B-frags: row n0+nt*16+l15, k = c
  {
    const u16* kp = kT + ((size_t)(b * NN + n0 + l15)) * NCQ + quad * 8;
#pragma unroll
    for (int nt = 0; nt < 4; ++nt)
#pragma unroll
      for (int ks = 0; ks < 4; ++ks) {
        kf[nt][ks] = *(const bf16x8*)(kp + (size_t)(nt * 16) * NCQ + ks * 32);
        asm volatile("" : "+v"(kf[nt][ks]));  // pin: no remat into the loop
      }
  }

  const u16* qbase = q2T + ((size_t)(b * NN + w * 1024 + l15)) * NCQ + quad * 8;
  float Z[4] = {0.f, 0.f, 0.f, 0.f};
  bf16x8 afA[4], afB[4];
#pragma unroll
  for (int ks = 0; ks < 4; ++ks) afA[ks] = *(const bf16x8*)(qbase + ks * 32);

  for (int it = 0; it < 64; it += 2) {
    // prefetch it+1 into afB, then compute it with afA
    {
      const u16* qp = qbase + (size_t)((it + 1) * 16) * NCQ;
#pragma unroll
      for (int ks = 0; ks < 4; ++ks) afB[ks] = *(const bf16x8*)(qp + ks * 32);
    }
#pragma unroll
    for (int nt = 0; nt < 4; ++nt) {
      f32x4 acc = {0.f, 0.f, 0.f, 0.f};
#pragma unroll
      for (int ks = 0; ks < 4; ++ks)
        acc = __builtin_amdgcn_mfma_f32_16x16x32_bf16(afA[ks], kf[nt][ks], acc, 0, 0, 0);
      Z[nt] += __builtin_amdgcn_exp2f(acc[0]) + __builtin_amdgcn_exp2f(acc[1]) +
               __builtin_amdgcn_exp2f(acc[2]) + __builtin_amdgcn_exp2f(acc[3]);
    }
    // prefetch it+2 into afA (wrap at the end; extra values unused), compute it+1
    {
      const int it2 = (it + 2) & 63;
      const u16* qp = qbase + (size_t)(it2 * 16) * NCQ;
#pragma unroll
      for (int ks = 0; ks < 4; ++ks) afA[ks] = *(const bf16x8*)(qp + ks * 32);
    }
#pragma unroll
    for (int nt = 0; nt < 4; ++nt) {
      f32x4 acc = {0.f, 0.f, 0.f, 0.f};
#pragma unroll
      for (int ks = 0; ks < 4; ++ks)
        acc = __builtin_amdgcn_mfma_f32_16x16x32_bf16(afB[ks], kf[nt][ks], acc, 0, 0, 0);
      Z[nt] += __builtin_amdgcn_exp2f(acc[0]) + __builtin_amdgcn_exp2f(acc[1]) +
               __builtin_amdgcn_exp2f(acc[2]) + __builtin_amdgcn_exp2f(acc[3]);
    }
  }
#pragma unroll
  for (int nt = 0; nt < 4; ++nt) {
    float z = Z[nt];
    z += __shfl_xor(z, 16, 64);
    z += __shfl_xor(z, 32, 64);
    Z[nt] = z;
  }
  if (lane < 16) {
#pragma unroll
    for (int nt = 0; nt < 4; ++nt) zbuf[w][nt * 16 + lane] = Z[nt];
  }
  __syncthreads();
  if (tid < 64) {
    const float z = zbuf[0][tid] + zbuf[1][tid] + zbuf[2][tid] + zbuf[3][tid];
    rbuf[b * NN + n0 + tid] = 1.0f / z;
  }
}

// -------------------------------------------- K2: v[c][n] *= r[n] in place --
__global__ __launch_bounds__(256, 4) void scale_kernel(
    u16* __restrict__ vr, const float* __restrict__ rbuf) {
  const int flat = (blockIdx.x * 256 + threadIdx.x) * 8;
  const int n = flat & (NN - 1);
  const int b = flat >> 20;
  const float4 r0 = *(const float4*)(rbuf + (b << 12) + n);
  const float4 r1 = *(const float4*)(rbuf + (b << 12) + n + 4);
  const ushort4 a0 = *(const ushort4*)(vr + flat);
  const ushort4 a1 = *(const ushort4*)(vr + flat + 4);
  ushort4 s0, s1;
  s0.x = f2bf(bf2f(a0.x) * r0.x); s0.y = f2bf(bf2f(a0.y) * r0.y);
  s0.z = f2bf(bf2f(a0.z) * r0.z); s0.w = f2bf(bf2f(a0.w) * r0.w);
  s1.x = f2bf(bf2f(a1.x) * r1.x); s1.y = f2bf(bf2f(a1.y) * r1.y);
  s1.z = f2bf(bf2f(a1.z) * r1.z); s1.w = f2bf(bf2f(a1.w) * r1.w);
  *(ushort4*)(vr + flat) = s0;
  *(ushort4*)(vr + flat + 4) = s1;
}

// ------------ K3: E' = exp2(S2) recompute, O = E'.vr^T, y = g*O + x --------
// grid 1024 = 8 b x 64 m-blocks x 2 c-halves. q-tile (64m x 128c) in LDS.
// R11 segment pipeline: seg t (t=1..63) = { S(t) with kf prefetched last
// seg || PV(t-1) with et written last seg } then raw barrier. The two
// streams are independent inside a segment -> MFMA/LDS/VALU overlap.
// et invariant unchanged: seg t writes et[t&1], reads et[(t-1)&1]; every
// write->read and read->overwrite pair is separated by one barrier.
__global__ __launch_bounds__(256, 4) void out_kernel(
    const u16* __restrict__ q2T, const u16* __restrict__ kT,
    const u16* __restrict__ vr,
    const void* xv, const void* gv,
    const void* bqv, const void* bkv, const void* bvv,
    void* outv) {
  __shared__ __align__(16) u16 qs[64][136];
  __shared__ __align__(16) u16 et[2][4][16][68];
  __shared__ int fl[2];
  const int tid = threadIdx.x;
  if (tid < 2) fl[tid] = 0;
  __syncthreads();
  if (scan_bad((const u16*)xv, 256, tid)) fl[0] = 1;
  if (scan_bad((const u16*)bqv, 64, tid) | scan_bad((const u16*)bkv, 64, tid) |
      scan_bad((const u16*)bvv, 64, tid)) fl[1] = 1;

  const int bid = blockIdx.x;
  const int b = bid & 7;
  const int r7 = bid >> 3;
  const int ch = r7 & 1;
  const int m0 = (r7 >> 1) << 6;
  const int w = tid >> 6, lane = tid & 63, l15 = lane & 15, quad = lane >> 4;

  {  // stage q2T[b][m0..m0+63][0..128) -> qs; thread t: row t>>2, 32 c
    const int mm = tid >> 2, ck = (tid & 3) * 32;
    const u16* src = q2T + ((size_t)(b * NN + m0 + mm)) * NCQ + ck;
#pragma unroll
    for (int j = 0; j < 4; ++j)
      *(bf16x8*)(&qs[mm][ck + j * 8]) = *(const bf16x8*)(src + j * 8);
  }
  __syncthreads();
  const bool fx = fl[0] != 0, fg = fl[1] != 0;

  f32x4 acc[8];  // acc[mg*2+ct]: m=m0+mg*16+quad*4+r, c=ch*128+w*32+ct*16+l15
#pragma unroll
  for (int i = 0; i < 8; ++i) acc[i] = (f32x4){0.f, 0.f, 0.f, 0.f};

  const u16* kb = kT + ((size_t)(b * NN + w * 16 + l15)) * NCQ + quad * 8;
  const u16* vb = vr + ((size_t)(b * NC + ch * 128 + w * 32 + l15)) * NN + quad * 8;

  // S stream: tile t -> et[pp]; kf = A-frags (row n), q frags from LDS (B)
  auto S_phase = [&](int pp, const bf16x8* kf) {
#pragma unroll
    for (int mg = 0; mg < 4; ++mg) {
      f32x4 s = {0.f, 0.f, 0.f, 0.f};
#pragma unroll
      for (int ks = 0; ks < 4; ++ks) {
        const bf16x8 qfr =
            *(const bf16x8*)(&qs[mg * 16 + l15][quad * 8 + ks * 32]);
        s = __builtin_amdgcn_mfma_f32_16x16x32_bf16(kf[ks], qfr, s, 0, 0, 0);
      }
      // s[r] = S2[m = m0+mg*16+l15][n = tile + w*16 + quad*4 + r]
      bf16x4 ev;
      ev[0] = (short)f2bf(__builtin_amdgcn_exp2f(s[0]));
      ev[1] = (short)f2bf(__builtin_amdgcn_exp2f(s[1]));
      ev[2] = (short)f2bf(__builtin_amdgcn_exp2f(s[2]));
      ev[3] = (short)f2bf(__builtin_amdgcn_exp2f(s[3]));
      *(bf16x4*)(&et[pp][mg][l15][w * 16 + quad * 4]) = ev;
    }
  };
  // PV stream: tile t-1 -> acc; reads et[pr] (written before last barrier)
  auto PV_phase = [&](int pr, const bf16x8* vf) {
#pragma unroll
    for (int mg = 0; mg < 4; ++mg)
#pragma unroll
      for (int ns = 0; ns < 2; ++ns) {
        const bf16x8 af =
            *(const bf16x8*)(&et[pr][mg][l15][ns * 32 + quad * 8]);
#pragma unroll
        for (int ct = 0; ct < 2; ++ct)
          acc[mg * 2 + ct] = __builtin_amdgcn_mfma_f32_16x16x32_bf16(
              af, vf[ct * 2 + ns], acc[mg * 2 + ct], 0, 0, 0);
      }
  };

  bf16x8 kc[4], kn[4], vf[4];
  // ---- prologue: seg 0 = S(0) only; prefetch kf(1) across the barrier ----
#pragma unroll
  for (int ks = 0; ks < 4; ++ks) kc[ks] = *(const bf16x8*)(kb + ks * 32);
  S_phase(0, kc);
#pragma unroll
  for (int ks = 0; ks < 4; ++ks)
    kn[ks] = *(const bf16x8*)(kb + (size_t)64 * NCQ + ks * 32);
  seg_barrier();
#pragma unroll
  for (int ks = 0; ks < 4; ++ks) kc[ks] = kn[ks];

  // ---- segments 1..63: { S(t) || PV(t-1) } ----
#pragma unroll 2
  for (int t = 1; t < 64; ++t) {
    const int pp = t & 1;
    const int nv = (t - 1) * 64;  // PV tile base
    // vf(t-1): issued here, consumed by PV after the independent S stream
#pragma unroll
    for (int ct = 0; ct < 2; ++ct)
#pragma unroll
      for (int ns = 0; ns < 2; ++ns)
        vf[ct * 2 + ns] =
            *(const bf16x8*)(vb + (size_t)(ct * 16) * NN + nv + ns * 32);
    // kf(t+1) prefetch (wrap at the end; extra values unused)
    {
      const int tn = (t < 63) ? (t + 1) : 0;
#pragma unroll
      for (int ks = 0; ks < 4; ++ks)
        kn[ks] = *(const bf16x8*)(kb + (size_t)(tn * 64) * NCQ + ks * 32);
    }
    S_phase(pp, kc);       // independent of PV below: operands prefetched
    PV_phase(pp ^ 1, vf);  // et written before last barrier; vf from above
    seg_barrier();
#pragma unroll
    for (int ks = 0; ks < 4; ++ks) kc[ks] = kn[ks];
  }

  // ---- epilogue: PV(63) ----
#pragma unroll
  for (int ct = 0; ct < 2; ++ct)
#pragma unroll
    for (int ns = 0; ns < 2; ++ns)
      vf[ct * 2 + ns] =
          *(const bf16x8*)(vb + (size_t)(ct * 16) * NN + 63 * 64 + ns * 32);
  PV_phase(1, vf);

  const float g = fg ? ((const float*)gv)[0] : bf2f(((const u16*)gv)[0]);
#pragma unroll
  for (int mg = 0; mg < 4; ++mg)
#pragma unroll
    for (int ct = 0; ct < 2; ++ct) {
      const int c = ch * 128 + w * 32 + ct * 16 + l15;           // D col = c
      const int m = m0 + mg * 16 + quad * 4;                     // D row = m
      const size_t base = ((size_t)(b * NC + c)) * NN + m;
      const f32x4 a = acc[mg * 2 + ct];
      if (fx) {
        const float4 xl = *(const float4*)((const float*)xv + base);
        float4 st;
        st.x = g * a[0] + xl.x; st.y = g * a[1] + xl.y;
        st.z = g * a[2] + xl.z; st.w = g * a[3] + xl.w;
        *(float4*)((float*)outv + base) = st;
      } else {
        const ushort4 xl = *(const ushort4*)((const u16*)xv + base);
        ushort4 st;
        st.x = f2bf(g * a[0] + bf2f(xl.x));
        st.y = f2bf(g * a[1] + bf2f(xl.y));
        st.z = f2bf(g * a[2] + bf2f(xl.z));
        st.w = f2bf(g * a[3] + bf2f(xl.w));
        *(ushort4*)((u16*)outv + base) = st;
      }
    }
}

// ---------------------------------------------------------------------------
extern "C" void kernel_launch(void* const* d_in, const int* in_sizes, int n_in,
                              void* d_out, int out_size, void* d_ws, size_t ws_size,
                              hipStream_t stream) {
  // ws: q2 8,388,608 | k 8,388,608 | v 16,777,216 = 32 MiB; r -> tail or d_out
  const size_t NEED = 33554432u;
  if (ws_size < NEED) return;

  char* ws = (char*)d_ws;
  u16* q2 = (u16*)(ws);
  u16* kk = (u16*)(ws + 8388608);
  u16* vv = (u16*)(ws + 16777216);
  float* rbuf = (ws_size >= NEED + 131072u) ? (float*)(ws + NEED) : (float*)d_out;

  qkv_kernel<<<512, 256, 0, stream>>>(d_in[0], d_in[1], d_in[2], d_in[3],
                                      d_in[4], d_in[5], d_in[6], q2, kk, vv);
  stats_kernel<<<512, 256, 0, stream>>>(q2, kk, rbuf);
  scale_kernel<<<4096, 256, 0, stream>>>(vv, rbuf);
  out_kernel<<<1024, 256, 0, stream>>>(q2, kk, vv, d_in[0], d_in[7],
                                       d_in[2], d_in[4], d_in[6], d_out);
}